// Round 1
// baseline (546.599 us; speedup 1.0000x reference)
//
#include <hip/hip_runtime.h>
#include <hip/hip_bf16.h>
#include <stdint.h>

#define N_NODES 8192
#define IN_F 512
#define OUT_F 256

typedef __attribute__((ext_vector_type(8))) short bf16x8;
typedef __attribute__((ext_vector_type(4))) float f32x4;

__device__ __forceinline__ unsigned short f2bf_rn(float f) {
  union { float f; unsigned u; } v; v.f = f;
  unsigned r = v.u + 0x7FFFu + ((v.u >> 16) & 1u);
  return (unsigned short)(r >> 16);
}
__device__ __forceinline__ float bf2f(unsigned short h) {
  union { unsigned u; float f; } v; v.u = ((unsigned)h) << 16;
  return v.f;
}

// ---------------------------------------------------------------------------
// K0: W [512][256] f32 -> Wt_h/Wt_l [256][512] bf16 (transposed, hi/lo split)
// ---------------------------------------------------------------------------
__global__ __launch_bounds__(256) void k0_prep_w(const float* __restrict__ W,
                                                 short* __restrict__ Wh,
                                                 short* __restrict__ Wl) {
  int k = blockIdx.x;        // 0..511
  int c = threadIdx.x;       // 0..255
  float v = W[(size_t)k * OUT_F + c];
  unsigned short h = f2bf_rn(v);
  unsigned short l = f2bf_rn(v - bf2f(h));
  Wh[(size_t)c * IN_F + k] = (short)h;
  Wl[(size_t)c * IN_F + k] = (short)l;
}

// ---------------------------------------------------------------------------
// K1: H = X @ W + bias.  MFMA bf16 3-product split (XhWh + XhWl + XlWh).
// grid: 128 rowblocks(BM=64) x 2 colblocks(BN=128); 256 thr = 4 waves.
// LDS tiles XOR-swizzled in 16B blocks: addr = row*64 + ((kb ^ (row&7))<<3).
// ---------------------------------------------------------------------------
__global__ __launch_bounds__(256) void k1_gemm_h(
    const float* __restrict__ X, const short* __restrict__ Wh,
    const short* __restrict__ Wl, const float* __restrict__ bias,
    float* __restrict__ H) {
  __shared__ __align__(16) short Xh[64 * 64], Xl[64 * 64];
  __shared__ __align__(16) short Wsh[128 * 64], Wsl[128 * 64];
  const int tid = threadIdx.x;
  const int rb = blockIdx.x >> 1, cb = blockIdx.x & 1;
  const int r0 = rb * 64, c0 = cb * 128;
  const int lane = tid & 63, wid = tid >> 6;

  f32x4 acc[8];
#pragma unroll
  for (int i = 0; i < 8; ++i) acc[i] = (f32x4){0.f, 0.f, 0.f, 0.f};

  const int sr = tid >> 2;          // staging row 0..63
  const int sk = (tid & 3) * 16;    // staging k offset

  for (int kc = 0; kc < IN_F; kc += 64) {
    // ---- stage X (f32 -> hi/lo bf16) ----
    const float* xp = X + (size_t)(r0 + sr) * IN_F + kc + sk;
#pragma unroll
    for (int q = 0; q < 2; ++q) {
      f32x4 v0 = *(const f32x4*)(xp + q * 8);
      f32x4 v1 = *(const f32x4*)(xp + q * 8 + 4);
      bf16x8 hv, lv;
#pragma unroll
      for (int j = 0; j < 4; ++j) {
        unsigned short h0 = f2bf_rn(v0[j]);
        hv[j] = (short)h0; lv[j] = (short)f2bf_rn(v0[j] - bf2f(h0));
        unsigned short h1 = f2bf_rn(v1[j]);
        hv[4 + j] = (short)h1; lv[4 + j] = (short)f2bf_rn(v1[j] - bf2f(h1));
      }
      int kb = (sk >> 3) + q;
      int off = sr * 64 + ((kb ^ (sr & 7)) << 3);
      *(bf16x8*)(Xh + off) = hv;
      *(bf16x8*)(Xl + off) = lv;
    }
    // ---- stage W (pre-split bf16, copy with swizzle) ----
#pragma unroll
    for (int it = 0; it < 4; ++it) {
      int u = it * 256 + tid;
      int col = u >> 3, kb = u & 7;
      size_t goff = (size_t)(c0 + col) * IN_F + kc + kb * 8;
      int off = col * 64 + ((kb ^ (col & 7)) << 3);
      *(bf16x8*)(Wsh + off) = *(const bf16x8*)(Wh + goff);
      *(bf16x8*)(Wsl + off) = *(const bf16x8*)(Wl + goff);
    }
    __syncthreads();
    // ---- compute ----
    const int arow = wid * 16 + (lane & 15);
    const int khalf = lane >> 4;
#pragma unroll
    for (int ks = 0; ks < 2; ++ks) {
      int kb = ks * 4 + khalf;
      int aoff = arow * 64 + ((kb ^ (arow & 7)) << 3);
      bf16x8 ah = *(const bf16x8*)(Xh + aoff);
      bf16x8 al = *(const bf16x8*)(Xl + aoff);
#pragma unroll
      for (int n = 0; n < 8; ++n) {
        int col = n * 16 + (lane & 15);
        int boff = col * 64 + ((kb ^ (col & 7)) << 3);
        bf16x8 bh = *(const bf16x8*)(Wsh + boff);
        bf16x8 bl = *(const bf16x8*)(Wsl + boff);
        acc[n] = __builtin_amdgcn_mfma_f32_16x16x32_bf16(ah, bh, acc[n], 0, 0, 0);
        acc[n] = __builtin_amdgcn_mfma_f32_16x16x32_bf16(ah, bl, acc[n], 0, 0, 0);
        acc[n] = __builtin_amdgcn_mfma_f32_16x16x32_bf16(al, bh, acc[n], 0, 0, 0);
      }
    }
    __syncthreads();
  }
  // epilogue: C/D layout col=lane&15, row=(lane>>4)*4+reg (m89/m91 verified)
  const int orow = r0 + wid * 16 + ((lane >> 4) << 2);
#pragma unroll
  for (int n = 0; n < 8; ++n) {
    int col = c0 + n * 16 + (lane & 15);
    float b = bias[col];
#pragma unroll
    for (int r = 0; r < 4; ++r)
      H[(size_t)(orow + r) * OUT_F + col] = acc[n][r] + b;
  }
}

// ---------------------------------------------------------------------------
// K2: s_dst[j] = H[j,:] . phi[256:512].  One wave per row.
// ---------------------------------------------------------------------------
__global__ __launch_bounds__(256) void k2_sdst(const float* __restrict__ H,
                                               const float* __restrict__ phi,
                                               float* __restrict__ sdst) {
  const int tid = threadIdx.x, lane = tid & 63, wid = tid >> 6;
  const int row = blockIdx.x * 4 + wid;
  f32x4 hv = *(const f32x4*)(H + (size_t)row * OUT_F + lane * 4);
  f32x4 pv = *(const f32x4*)(phi + OUT_F + lane * 4);
  float s = hv[0] * pv[0] + hv[1] * pv[1] + hv[2] * pv[2] + hv[3] * pv[3];
#pragma unroll
  for (int off = 32; off; off >>= 1) s += __shfl_xor(s, off);
  if (lane == 0) sdst[row] = s;
}

// ---------------------------------------------------------------------------
// K3: gmax = max(s_dst); e[j] = exp(s_dst[j] - gmax).  Single block.
// ---------------------------------------------------------------------------
__global__ __launch_bounds__(1024) void k3_maxexp(const float* __restrict__ sdst,
                                                  float* __restrict__ e) {
  __shared__ float red[16];
  const int tid = threadIdx.x;
  float m = -1e30f;
  for (int j = tid; j < N_NODES; j += 1024) m = fmaxf(m, sdst[j]);
#pragma unroll
  for (int off = 32; off; off >>= 1) m = fmaxf(m, __shfl_xor(m, off));
  if ((tid & 63) == 0) red[tid >> 6] = m;
  __syncthreads();
  float gm = red[0];
#pragma unroll
  for (int i = 1; i < 16; ++i) gm = fmaxf(gm, red[i]);
  for (int j = tid; j < N_NODES; j += 1024) e[j] = expf(sdst[j] - gm);
}

// ---------------------------------------------------------------------------
// K4: B = (e ⊙ H)^T as hi/lo bf16, [256 cols][8192 k].  LDS transpose 64x64.
// ---------------------------------------------------------------------------
__global__ __launch_bounds__(256) void k4_build_b(const float* __restrict__ H,
                                                  const float* __restrict__ e,
                                                  short* __restrict__ Bh,
                                                  short* __restrict__ Bl) {
  __shared__ float t[64][65];
  const int tid = threadIdx.x;
  const int tx = tid & 63, ty = tid >> 6;
  const int j0 = (blockIdx.x >> 2) * 64;   // node tile
  const int c0 = (blockIdx.x & 3) * 64;    // feature tile
#pragma unroll
  for (int i = 0; i < 16; ++i) {
    int r = ty + i * 4;
    t[r][tx] = H[(size_t)(j0 + r) * OUT_F + c0 + tx];
  }
  __syncthreads();
  const float ej = e[j0 + tx];
#pragma unroll
  for (int i = 0; i < 16; ++i) {
    int c = c0 + ty + i * 4;
    float v = ej * t[tx][ty + i * 4];
    unsigned short h = f2bf_rn(v);
    unsigned short l = f2bf_rn(v - bf2f(h));
    Bh[(size_t)c * N_NODES + j0 + tx] = (short)h;
    Bl[(size_t)c * N_NODES + j0 + tx] = (short)l;
  }
}

// ---------------------------------------------------------------------------
// K5: main GEMM.  part[ks] += mask(adj|I) @ (Bh+Bl); denom on VALU in staging.
// grid: 64 rowblocks(BM=128) x ksplit; 512 thr = 8 waves, wave = 16 rows x 256.
// adj converted to bf16 {0,1} in-register (read exactly once from HBM).
// ---------------------------------------------------------------------------
__global__ __launch_bounds__(512) void k5_main(
    const int* __restrict__ adj, const short* __restrict__ Bh,
    const short* __restrict__ Bl, const float* __restrict__ e,
    float* __restrict__ part, float* __restrict__ dpartg, int kchunk) {
  __shared__ __align__(16) short Alds[128 * 64];
  __shared__ __align__(16) short Bhl[256 * 64];
  __shared__ __align__(16) short Bll[256 * 64];

  const int tid = threadIdx.x;
  const int rb = blockIdx.x & 63;
  const int ksi = blockIdx.x >> 6;
  const int r0 = rb * 128;
  const long kbeg = (long)ksi * kchunk;
  const int lane = tid & 63, wid = tid >> 6;

  f32x4 acc[16];
#pragma unroll
  for (int i = 0; i < 16; ++i) acc[i] = (f32x4){0.f, 0.f, 0.f, 0.f};

  const int sr = tid >> 2;          // staging row 0..127
  const int sk = (tid & 3) * 16;
  const int irow = r0 + sr;
  float dsum = 0.f;

  for (long kc = kbeg; kc < kbeg + kchunk; kc += 64) {
    // ---- stage A: adj -> {0,1} bf16 mask (+diag), accumulate denom ----
    const int* ap = adj + (size_t)irow * N_NODES + kc + sk;
    const float* ep = e + kc + sk;
#pragma unroll
    for (int q = 0; q < 2; ++q) {
      int4 i0 = *(const int4*)(ap + q * 8);
      int4 i1 = *(const int4*)(ap + q * 8 + 4);
      f32x4 e0 = *(const f32x4*)(ep + q * 8);
      f32x4 e1 = *(const f32x4*)(ep + q * 8 + 4);
      long kg = kc + sk + q * 8;
      int vals[8] = {i0.x, i0.y, i0.z, i0.w, i1.x, i1.y, i1.z, i1.w};
      bf16x8 mv;
#pragma unroll
      for (int j = 0; j < 8; ++j) {
        bool m = (vals[j] != 0) || (kg + j == irow);
        mv[j] = m ? (short)0x3F80 : (short)0;
        float ej = (j < 4) ? e0[j] : e1[j - 4];
        dsum += m ? ej : 0.f;
      }
      int kb = (sk >> 3) + q;
      int off = sr * 64 + ((kb ^ (sr & 7)) << 3);
      *(bf16x8*)(Alds + off) = mv;
    }
    // ---- stage B hi/lo (copy with swizzle) ----
#pragma unroll
    for (int it = 0; it < 4; ++it) {
      int u = it * 512 + tid;
      int col = u >> 3, kb = u & 7;
      size_t goff = (size_t)col * N_NODES + kc + kb * 8;
      int off = col * 64 + ((kb ^ (col & 7)) << 3);
      *(bf16x8*)(Bhl + off) = *(const bf16x8*)(Bh + goff);
      *(bf16x8*)(Bll + off) = *(const bf16x8*)(Bl + goff);
    }
    __syncthreads();
    // ---- compute: 2 kslices x 16 coltiles x {hi,lo} ----
    const int arow = wid * 16 + (lane & 15);
    const int khalf = lane >> 4;
#pragma unroll
    for (int ks = 0; ks < 2; ++ks) {
      int kb = ks * 4 + khalf;
      int aoff = arow * 64 + ((kb ^ (arow & 7)) << 3);
      bf16x8 a = *(const bf16x8*)(Alds + aoff);
#pragma unroll
      for (int n = 0; n < 16; ++n) {
        int col = n * 16 + (lane & 15);
        int boff = col * 64 + ((kb ^ (col & 7)) << 3);
        bf16x8 bh = *(const bf16x8*)(Bhl + boff);
        bf16x8 bl = *(const bf16x8*)(Bll + boff);
        acc[n] = __builtin_amdgcn_mfma_f32_16x16x32_bf16(a, bh, acc[n], 0, 0, 0);
        acc[n] = __builtin_amdgcn_mfma_f32_16x16x32_bf16(a, bl, acc[n], 0, 0, 0);
      }
    }
    __syncthreads();
  }
  // denom: reduce the 4 threads sharing a staging row
  dsum += __shfl_xor(dsum, 1);
  dsum += __shfl_xor(dsum, 2);
  if ((tid & 3) == 0) dpartg[(size_t)ksi * N_NODES + irow] = dsum;
  // numerator partial
  const int orow0 = r0 + wid * 16 + ((lane >> 4) << 2);
  float* pbase = part + (size_t)ksi * N_NODES * OUT_F;
#pragma unroll
  for (int n = 0; n < 16; ++n) {
    int col = n * 16 + (lane & 15);
#pragma unroll
    for (int r = 0; r < 4; ++r)
      pbase[(size_t)(orow0 + r) * OUT_F + col] = acc[n][r];
  }
}

// ---------------------------------------------------------------------------
// K6: out[i,f] = sum_p part[p][i][f] / sum_p denom[p][i]
// ---------------------------------------------------------------------------
__global__ __launch_bounds__(256) void k6_final(const float* __restrict__ part,
                                                const float* __restrict__ dpart,
                                                float* __restrict__ out, int ksplit) {
  const int i = blockIdx.x, f = threadIdx.x;
  float num = 0.f, den = 0.f;
  for (int p = 0; p < ksplit; ++p) {
    num += part[((size_t)p * N_NODES + i) * OUT_F + f];
    den += dpart[(size_t)p * N_NODES + i];
  }
  out[(size_t)i * OUT_F + f] = num / den;
}

// ---------------------------------------------------------------------------
extern "C" void kernel_launch(void* const* d_in, const int* in_sizes, int n_in,
                              void* d_out, int out_size, void* d_ws, size_t ws_size,
                              hipStream_t stream) {
  const float* x    = (const float*)d_in[0];
  const int*   adj  = (const int*)d_in[1];
  const float* w    = (const float*)d_in[2];
  const float* bias = (const float*)d_in[3];
  const float* phi  = (const float*)d_in[4];
  float* out = (float*)d_out;
  char* ws = (char*)d_ws;

  size_t off = 0;
  auto alloc = [&](size_t bytes) {
    size_t o = off; off += (bytes + 255) & ~(size_t)255; return o;
  };
  size_t oH  = alloc((size_t)N_NODES * OUT_F * 4);
  size_t oWh = alloc((size_t)OUT_F * IN_F * 2);
  size_t oWl = alloc((size_t)OUT_F * IN_F * 2);
  size_t oSd = alloc((size_t)N_NODES * 4);
  size_t oE  = alloc((size_t)N_NODES * 4);
  size_t oBh = alloc((size_t)OUT_F * N_NODES * 2);
  size_t oBl = alloc((size_t)OUT_F * N_NODES * 2);
  int ksplit = 4;
  while (ksplit > 1 &&
         off + (size_t)ksplit * ((size_t)N_NODES * OUT_F * 4 + N_NODES * 4 + 512) > ws_size)
    ksplit >>= 1;
  size_t oPart = alloc((size_t)ksplit * N_NODES * OUT_F * 4);
  size_t oDp   = alloc((size_t)ksplit * N_NODES * 4);

  float* H  = (float*)(ws + oH);
  short* Wh = (short*)(ws + oWh);
  short* Wl = (short*)(ws + oWl);
  float* Sd = (float*)(ws + oSd);
  float* E  = (float*)(ws + oE);
  short* Bh = (short*)(ws + oBh);
  short* Bl = (short*)(ws + oBl);
  float* Part = (float*)(ws + oPart);
  float* Dp   = (float*)(ws + oDp);

  k0_prep_w<<<IN_F, OUT_F, 0, stream>>>(w, Wh, Wl);
  k1_gemm_h<<<256, 256, 0, stream>>>(x, Wh, Wl, bias, H);
  k2_sdst<<<N_NODES / 4, 256, 0, stream>>>(H, phi, Sd);
  k3_maxexp<<<1, 1024, 0, stream>>>(Sd, E);
  k4_build_b<<<512, 256, 0, stream>>>(H, E, Bh, Bl);
  k5_main<<<64 * ksplit, 512, 0, stream>>>(adj, Bh, Bl, E, Part, Dp, N_NODES / ksplit);
  k6_final<<<N_NODES, 256, 0, stream>>>(Part, Dp, out, ksplit);
}

// Round 4
// 482.980 us; speedup vs baseline: 1.1317x; 1.1317x over previous
//
#include <hip/hip_runtime.h>
#include <hip/hip_bf16.h>
#include <stdint.h>

#define N_NODES 8192
#define IN_F 512
#define OUT_F 256
#define KSPLIT 4

typedef __attribute__((ext_vector_type(8))) short bf16x8;
typedef __attribute__((ext_vector_type(4))) float f32x4;

__device__ __forceinline__ unsigned short f2bf_rn(float f) {
  union { float f; unsigned u; } v; v.f = f;
  unsigned r = v.u + 0x7FFFu + ((v.u >> 16) & 1u);
  return (unsigned short)(r >> 16);
}
__device__ __forceinline__ float bf2f(unsigned short h) {
  union { unsigned u; float f; } v; v.u = ((unsigned)h) << 16;
  return v.f;
}

__device__ __forceinline__ void gload_lds16(const void* g, void* l) {
  __builtin_amdgcn_global_load_lds(
      (const __attribute__((address_space(1))) unsigned int*)g,
      (__attribute__((address_space(3))) unsigned int*)l, 16, 0, 0);
}

// expand 8 mask bytes (each 0/1) -> 8 bf16 (0.0/1.0)
__device__ __forceinline__ bf16x8 expand8(uint2 b) {
  unsigned c0 = b.x, c1 = b.x >> 16, c2 = b.y, c3 = b.y >> 16;
  uint4 q;
  q.x = ((c0 & 1u) | ((c0 & 0x100u) << 8)) * 0x3F80u;
  q.y = ((c1 & 1u) | ((c1 & 0x100u) << 8)) * 0x3F80u;
  q.z = ((c2 & 1u) | ((c2 & 0x100u) << 8)) * 0x3F80u;
  q.w = ((c3 & 1u) | ((c3 & 0x100u) << 8)) * 0x3F80u;
  union { uint4 u; bf16x8 v; } r; r.u = q;
  return r.v;
}

// ---------------------------------------------------------------------------
// K0: W [512][256] f32 -> Wt_h/Wt_l [256][512] bf16 (transposed, hi/lo split)
// ---------------------------------------------------------------------------
__global__ __launch_bounds__(256) void k0_prep_w(const float* __restrict__ W,
                                                 short* __restrict__ Wh,
                                                 short* __restrict__ Wl) {
  int k = blockIdx.x;
  int c = threadIdx.x;
  float v = W[(size_t)k * OUT_F + c];
  unsigned short h = f2bf_rn(v);
  unsigned short l = f2bf_rn(v - bf2f(h));
  Wh[(size_t)c * IN_F + k] = (short)h;
  Wl[(size_t)c * IN_F + k] = (short)l;
}

// ---------------------------------------------------------------------------
// K1: H = X @ W + bias  (known-correct)
// ---------------------------------------------------------------------------
__global__ __launch_bounds__(256) void k1_gemm_h(
    const float* __restrict__ X, const short* __restrict__ Wh,
    const short* __restrict__ Wl, const float* __restrict__ bias,
    float* __restrict__ H) {
  __shared__ __align__(16) short Xh[64 * 64], Xl[64 * 64];
  __shared__ __align__(16) short Wsh[128 * 64], Wsl[128 * 64];
  const int tid = threadIdx.x;
  const int rb = blockIdx.x >> 1, cb = blockIdx.x & 1;
  const int r0 = rb * 64, c0 = cb * 128;
  const int lane = tid & 63, wid = tid >> 6;

  f32x4 acc[8];
#pragma unroll
  for (int i = 0; i < 8; ++i) acc[i] = (f32x4){0.f, 0.f, 0.f, 0.f};

  const int sr = tid >> 2;
  const int sk = (tid & 3) * 16;

  for (int kc = 0; kc < IN_F; kc += 64) {
    const float* xp = X + (size_t)(r0 + sr) * IN_F + kc + sk;
#pragma unroll
    for (int q = 0; q < 2; ++q) {
      f32x4 v0 = *(const f32x4*)(xp + q * 8);
      f32x4 v1 = *(const f32x4*)(xp + q * 8 + 4);
      bf16x8 hv, lv;
#pragma unroll
      for (int j = 0; j < 4; ++j) {
        unsigned short h0 = f2bf_rn(v0[j]);
        hv[j] = (short)h0; lv[j] = (short)f2bf_rn(v0[j] - bf2f(h0));
        unsigned short h1 = f2bf_rn(v1[j]);
        hv[4 + j] = (short)h1; lv[4 + j] = (short)f2bf_rn(v1[j] - bf2f(h1));
      }
      int kb = (sk >> 3) + q;
      int off = sr * 64 + ((kb ^ (sr & 7)) << 3);
      *(bf16x8*)(Xh + off) = hv;
      *(bf16x8*)(Xl + off) = lv;
    }
#pragma unroll
    for (int it = 0; it < 4; ++it) {
      int u = it * 256 + tid;
      int col = u >> 3, kb = u & 7;
      size_t goff = (size_t)(c0 + col) * IN_F + kc + kb * 8;
      int off = col * 64 + ((kb ^ (col & 7)) << 3);
      *(bf16x8*)(Wsh + off) = *(const bf16x8*)(Wh + goff);
      *(bf16x8*)(Wsl + off) = *(const bf16x8*)(Wl + goff);
    }
    __syncthreads();
    const int arow = wid * 16 + (lane & 15);
    const int khalf = lane >> 4;
#pragma unroll
    for (int ks = 0; ks < 2; ++ks) {
      int kb = ks * 4 + khalf;
      int aoff = arow * 64 + ((kb ^ (arow & 7)) << 3);
      bf16x8 ah = *(const bf16x8*)(Xh + aoff);
      bf16x8 al = *(const bf16x8*)(Xl + aoff);
#pragma unroll
      for (int n = 0; n < 8; ++n) {
        int col = n * 16 + (lane & 15);
        int boff = col * 64 + ((kb ^ (col & 7)) << 3);
        bf16x8 bh = *(const bf16x8*)(Wsh + boff);
        bf16x8 bl = *(const bf16x8*)(Wsl + boff);
        acc[n] = __builtin_amdgcn_mfma_f32_16x16x32_bf16(ah, bh, acc[n], 0, 0, 0);
        acc[n] = __builtin_amdgcn_mfma_f32_16x16x32_bf16(ah, bl, acc[n], 0, 0, 0);
        acc[n] = __builtin_amdgcn_mfma_f32_16x16x32_bf16(al, bh, acc[n], 0, 0, 0);
      }
    }
    __syncthreads();
  }
  const int orow = r0 + wid * 16 + ((lane >> 4) << 2);
#pragma unroll
  for (int n = 0; n < 8; ++n) {
    int col = c0 + n * 16 + (lane & 15);
    float b = bias[col];
#pragma unroll
    for (int r = 0; r < 4; ++r)
      H[(size_t)(orow + r) * OUT_F + col] = acc[n][r] + b;
  }
}

// ---------------------------------------------------------------------------
// K2: s_dst[j] = H[j,:] . phi[256:512]; also per-block max -> blockmax[2048]
// ---------------------------------------------------------------------------
__global__ __launch_bounds__(256) void k2_sdst(const float* __restrict__ H,
                                               const float* __restrict__ phi,
                                               float* __restrict__ sdst,
                                               float* __restrict__ blockmax) {
  __shared__ float r4[4];
  const int tid = threadIdx.x, lane = tid & 63, wid = tid >> 6;
  const int row = blockIdx.x * 4 + wid;
  f32x4 hv = *(const f32x4*)(H + (size_t)row * OUT_F + lane * 4);
  f32x4 pv = *(const f32x4*)(phi + OUT_F + lane * 4);
  float s = hv[0] * pv[0] + hv[1] * pv[1] + hv[2] * pv[2] + hv[3] * pv[3];
#pragma unroll
  for (int off = 32; off; off >>= 1) s += __shfl_xor(s, off);
  if (lane == 0) { sdst[row] = s; r4[wid] = s; }
  __syncthreads();
  if (tid == 0)
    blockmax[blockIdx.x] = fmaxf(fmaxf(r4[0], r4[1]), fmaxf(r4[2], r4[3]));
}

// ---------------------------------------------------------------------------
// K4: gmax = max(blockmax); e = exp(sdst-gmax);
//     Bs = (e ⊙ H)^T hi/lo bf16, PRE-SWIZZLED in global so k5's linear
//     global_load_lds lands XOR-swizzled in LDS.
//     Bs layout: plane0(hi) cols 0..255, plane1(lo) at +256*N. Within each
//     64-k chunk: Bs[c][j0 + (tx ^ ((c&7)<<3))] = B[c][j0+tx].
// ---------------------------------------------------------------------------
__global__ __launch_bounds__(256) void k4_build(const float* __restrict__ H,
                                                const float* __restrict__ sdst,
                                                const float* __restrict__ blockmax,
                                                short* __restrict__ Bs,
                                                float* __restrict__ e) {
  __shared__ float t[64][65];
  __shared__ float red[4];
  const int tid = threadIdx.x;
  float m = -1e30f;
  for (int i = tid; i < 2048; i += 256) m = fmaxf(m, blockmax[i]);
#pragma unroll
  for (int off = 32; off; off >>= 1) m = fmaxf(m, __shfl_xor(m, off));
  if ((tid & 63) == 0) red[tid >> 6] = m;
  __syncthreads();
  const float gmax = fmaxf(fmaxf(red[0], red[1]), fmaxf(red[2], red[3]));

  const int tx = tid & 63, ty = tid >> 6;
  const int j0 = (blockIdx.x >> 2) * 64;
  const int c0 = (blockIdx.x & 3) * 64;
#pragma unroll
  for (int i = 0; i < 16; ++i)
    t[ty + i * 4][tx] = H[(size_t)(j0 + ty + i * 4) * OUT_F + c0 + tx];
  __syncthreads();
  const float ej = expf(sdst[j0 + tx] - gmax);
#pragma unroll
  for (int i = 0; i < 16; ++i) {
    int c = c0 + ty + i * 4;
    float v = ej * t[tx][ty + i * 4];
    unsigned short h = f2bf_rn(v);
    unsigned short l = f2bf_rn(v - bf2f(h));
    size_t kidx = (size_t)j0 + (tx ^ ((c & 7) << 3));
    Bs[(size_t)c * N_NODES + kidx] = (short)h;
    Bs[(size_t)(256 + c) * N_NODES + kidx] = (short)l;
  }
  if (c0 == 0 && tid < 64) e[j0 + tid] = expf(sdst[j0 + tid] - gmax);
}

// ---------------------------------------------------------------------------
// K5: part[ksi] = adj @ (e⊙H) via MFMA, single-barrier prefetch pipeline.
// BM=128, BN=256, BK=64; 512 thr = 8 waves (2 row-grp x 4 col-grp).
// A: adj -> byte mask, dbuf LDS 16KB (XOR-swizzled 8B groups), expanded to
//    bf16 in-register at compute. Diagonal handled in k6.
// B: dbuf 128KB via global_load_lds from pre-swizzled Bs. Total LDS 144KB.
// Denominator (sum adj*e per row) on VALU during staging.
// ---------------------------------------------------------------------------
__global__ __launch_bounds__(512) void k5_main(
    const int* __restrict__ adj, const short* __restrict__ Bs,
    const float* __restrict__ e, float* __restrict__ part,
    float* __restrict__ dpartg, int kchunk) {
  __shared__ __align__(16) unsigned char Ab[2][128 * 64];   // 16 KB
  __shared__ __align__(16) short Bb[2][2 * 256 * 64];       // 128 KB

  const int tid = threadIdx.x;
  // XCD swizzle: 256 wgs, 8 XCDs, 32/XCD -> each XCD owns one ksi-pair chunk
  const int bid = (int)(blockIdx.x & 7) * 32 + (int)(blockIdx.x >> 3);
  const int rb = bid & 63, ksi = bid >> 6;
  const int r0 = rb * 128;
  const long kbeg = (long)ksi * kchunk;
  const int lane = tid & 63, wid = tid >> 6;
  const int wr = wid >> 2, wc = wid & 3;

  f32x4 acc[4][4];
#pragma unroll
  for (int mi = 0; mi < 4; ++mi)
#pragma unroll
    for (int ni = 0; ni < 4; ++ni) acc[mi][ni] = (f32x4){0.f, 0.f, 0.f, 0.f};

  const int sr = tid >> 2;          // staging row 0..127
  const int skq = tid & 3;          // k quarter
  const int sk = skq * 16;
  const int irow = r0 + sr;
  float dsum = 0.f;

  int4 a0, a1, a2, a3;
  f32x4 ev0, ev1, ev2, ev3;

  auto issueA = [&](long kc) {
    const int* ap = adj + (size_t)irow * N_NODES + kc + sk;
    a0 = ((const int4*)ap)[0]; a1 = ((const int4*)ap)[1];
    a2 = ((const int4*)ap)[2]; a3 = ((const int4*)ap)[3];
    const float* ep = e + kc + sk;
    ev0 = ((const f32x4*)ep)[0]; ev1 = ((const f32x4*)ep)[1];
    ev2 = ((const f32x4*)ep)[2]; ev3 = ((const f32x4*)ep)[3];
  };
  auto issueB = [&](long kc, int buf) {
    const int p = wid >> 2;     // plane 0/1
    const int cg = wid & 3;     // 64-col group
    const short* base = Bs + (size_t)p * 256 * N_NODES + kc;
#pragma unroll
    for (int i = 0; i < 8; ++i) {
      int col = cg * 64 + i * 8 + (lane >> 3);
      const short* g = base + (size_t)col * N_NODES + (lane & 7) * 8;
      short* l = &Bb[buf][(p * 256 + cg * 64 + i * 8) * 64];
      gload_lds16(g, l);
    }
  };
  auto finishA = [&](int buf) {
    // dsum += adj * e  (adj in {0,1})
    dsum += (float)a0.x * ev0[0] + (float)a0.y * ev0[1] +
            (float)a0.z * ev0[2] + (float)a0.w * ev0[3];
    dsum += (float)a1.x * ev1[0] + (float)a1.y * ev1[1] +
            (float)a1.z * ev1[2] + (float)a1.w * ev1[3];
    dsum += (float)a2.x * ev2[0] + (float)a2.y * ev2[1] +
            (float)a2.z * ev2[2] + (float)a2.w * ev2[3];
    dsum += (float)a3.x * ev3[0] + (float)a3.y * ev3[1] +
            (float)a3.z * ev3[2] + (float)a3.w * ev3[3];
    unsigned u0 = (unsigned)a0.x | ((unsigned)a0.y << 8) |
                  ((unsigned)a0.z << 16) | ((unsigned)a0.w << 24);
    unsigned u1 = (unsigned)a1.x | ((unsigned)a1.y << 8) |
                  ((unsigned)a1.z << 16) | ((unsigned)a1.w << 24);
    unsigned u2 = (unsigned)a2.x | ((unsigned)a2.y << 8) |
                  ((unsigned)a2.z << 16) | ((unsigned)a2.w << 24);
    unsigned u3 = (unsigned)a3.x | ((unsigned)a3.y << 8) |
                  ((unsigned)a3.z << 16) | ((unsigned)a3.w << 24);
    const int g0 = skq * 2, g1 = g0 + 1;
    uint2 w0; w0.x = u0; w0.y = u1;
    uint2 w1; w1.x = u2; w1.y = u3;
    *(uint2*)&Ab[buf][sr * 64 + ((g0 ^ (sr & 7)) << 3)] = w0;
    *(uint2*)&Ab[buf][sr * 64 + ((g1 ^ (sr & 7)) << 3)] = w1;
  };
  auto compute = [&](int buf) {
#pragma unroll
    for (int ks = 0; ks < 2; ++ks) {
      const int kb = ks * 4 + (lane >> 4);
      bf16x8 af[4];
#pragma unroll
      for (int mi = 0; mi < 4; ++mi) {
        int row = wr * 64 + mi * 16 + (lane & 15);
        uint2 b = *(const uint2*)&Ab[buf][row * 64 + ((kb ^ (row & 7)) << 3)];
        af[mi] = expand8(b);
      }
#pragma unroll
      for (int ni = 0; ni < 4; ++ni) {
        int col = wc * 64 + ni * 16 + (lane & 15);
        int so = (kb ^ (col & 7)) << 3;
        bf16x8 bh = *(const bf16x8*)&Bb[buf][col * 64 + so];
        bf16x8 bl = *(const bf16x8*)&Bb[buf][(256 + col) * 64 + so];
#pragma unroll
        for (int mi = 0; mi < 4; ++mi) {
          acc[mi][ni] = __builtin_amdgcn_mfma_f32_16x16x32_bf16(af[mi], bh, acc[mi][ni], 0, 0, 0);
          acc[mi][ni] = __builtin_amdgcn_mfma_f32_16x16x32_bf16(af[mi], bl, acc[mi][ni], 0, 0, 0);
        }
      }
    }
  };

  // prologue: stage tile 0
  issueA(kbeg); issueB(kbeg, 0); finishA(0);
  __syncthreads();

  const int NT = kchunk >> 6;
  for (int t = 0; t < NT; ++t) {
    const int cur = t & 1;
    if (t + 1 < NT) {
      const long kc = kbeg + (long)(t + 1) * 64;
      issueA(kc);            // adj+e loads in flight during compute
      issueB(kc, cur ^ 1);   // async direct-to-LDS, drained by syncthreads
    }
    compute(cur);
    if (t + 1 < NT) finishA(cur ^ 1);
    __syncthreads();
  }

  // denominator: reduce 4 threads sharing a staging row
  dsum += __shfl_xor(dsum, 1);
  dsum += __shfl_xor(dsum, 2);
  if ((tid & 3) == 0) dpartg[(size_t)ksi * N_NODES + irow] = dsum;

  // numerator partial
  float* pbase = part + (size_t)ksi * N_NODES * OUT_F;
  const int orow0 = r0 + wr * 64 + ((lane >> 4) << 2);
#pragma unroll
  for (int mi = 0; mi < 4; ++mi) {
    int orow = orow0 + mi * 16;
#pragma unroll
    for (int ni = 0; ni < 4; ++ni) {
      int col = wc * 64 + ni * 16 + (lane & 15);
#pragma unroll
      for (int r = 0; r < 4; ++r)
        pbase[(size_t)(orow + r) * OUT_F + col] = acc[mi][ni][r];
    }
  }
}

// ---------------------------------------------------------------------------
// K6: out[i,f] = (sum_p part + diag-fix) / (sum_p dpart + diag-fix)
// diag: mask = adj|I, k5 used adj only; add e_i*H_i (and e_i) iff adj[i][i]==0
// ---------------------------------------------------------------------------
__global__ __launch_bounds__(256) void k6_final(const float* __restrict__ part,
                                                const float* __restrict__ dpart,
                                                const float* __restrict__ H,
                                                const float* __restrict__ e,
                                                const int* __restrict__ adj,
                                                float* __restrict__ out) {
  const int i = blockIdx.x, f = threadIdx.x;
  float num = 0.f, den = 0.f;
#pragma unroll
  for (int p = 0; p < KSPLIT; ++p) {
    num += part[((size_t)p * N_NODES + i) * OUT_F + f];
    den += dpart[(size_t)p * N_NODES + i];
  }
  if (adj[(size_t)i * N_NODES + i] == 0) {
    float ei = e[i];
    num += ei * H[(size_t)i * OUT_F + f];
    den += ei;
  }
  out[(size_t)i * OUT_F + f] = num / den;
}

// ---------------------------------------------------------------------------
extern "C" void kernel_launch(void* const* d_in, const int* in_sizes, int n_in,
                              void* d_out, int out_size, void* d_ws, size_t ws_size,
                              hipStream_t stream) {
  const float* x    = (const float*)d_in[0];
  const int*   adj  = (const int*)d_in[1];
  const float* w    = (const float*)d_in[2];
  const float* bias = (const float*)d_in[3];
  const float* phi  = (const float*)d_in[4];
  float* out = (float*)d_out;
  char* ws = (char*)d_ws;

  size_t off = 0;
  auto alloc = [&](size_t bytes) {
    size_t o = off; off += (bytes + 255) & ~(size_t)255; return o;
  };
  size_t oH   = alloc((size_t)N_NODES * OUT_F * 4);
  size_t oWh  = alloc((size_t)OUT_F * IN_F * 2);
  size_t oWl  = alloc((size_t)OUT_F * IN_F * 2);
  size_t oSd  = alloc((size_t)N_NODES * 4);
  size_t oBm  = alloc((size_t)2048 * 4);
  size_t oE   = alloc((size_t)N_NODES * 4);
  size_t oBs  = alloc((size_t)2 * OUT_F * N_NODES * 2);
  size_t oPart = alloc((size_t)KSPLIT * N_NODES * OUT_F * 4);
  size_t oDp   = alloc((size_t)KSPLIT * N_NODES * 4);
  (void)oDp; (void)ws_size;

  float* H   = (float*)(ws + oH);
  short* Wh  = (short*)(ws + oWh);
  short* Wl  = (short*)(ws + oWl);
  float* Sd  = (float*)(ws + oSd);
  float* Bm  = (float*)(ws + oBm);
  float* E   = (float*)(ws + oE);
  short* Bs  = (short*)(ws + oBs);
  float* Part = (float*)(ws + oPart);
  float* Dp   = (float*)(ws + oDp);

  k0_prep_w<<<IN_F, OUT_F, 0, stream>>>(w, Wh, Wl);
  k1_gemm_h<<<256, 256, 0, stream>>>(x, Wh, Wl, bias, H);
  k2_sdst<<<N_NODES / 4, 256, 0, stream>>>(H, phi, Sd, Bm);
  k4_build<<<512, 256, 0, stream>>>(H, Sd, Bm, Bs, E);
  k5_main<<<64 * KSPLIT, 512, 0, stream>>>(adj, Bs, E, Part, Dp, N_NODES / KSPLIT);
  k6_final<<<N_NODES, 256, 0, stream>>>(Part, Dp, H, E, adj, out);
}